// Round 10
// baseline (993.068 us; speedup 1.0000x reference)
//
#include <hip/hip_runtime.h>

#define N_NODESC 100000
#define N_EDGESC 1600000
#define N_GRAPHSC 512
#define DIMC 128
#define NLC 3
#define NBUCK 196      // ceil(100000/512)
#define EPB 4096       // edges per block in bucket scatter
#define ECAP 10240     // fixed per-bucket capacity (mean 8192, sigma~90)
#define BCAP 12288     // LDS staging capacity per bucket
#define NDEG 64        // degree buckets for load-balance sort

typedef __bf16 bf16_t;
typedef __bf16 bf16x2 __attribute__((ext_vector_type(2)));
typedef __bf16 bf16x4 __attribute__((ext_vector_type(4)));
typedef __bf16 bf16x8 __attribute__((ext_vector_type(8)));
typedef float f32x4 __attribute__((ext_vector_type(4)));

__device__ inline float bl(unsigned u) { union { unsigned x; float f; } c; c.x = u << 16; return c.f; }
__device__ inline float bh(unsigned u) { union { unsigned x; float f; } c; c.x = u & 0xffff0000u; return c.f; }
__device__ inline unsigned pk(float a, float b) {
    bf16x2 p; p[0] = (bf16_t)a; p[1] = (bf16_t)b;
    unsigned u; __builtin_memcpy(&u, &p, 4); return u;
}

// ---------- pack W^T (f32) into MFMA-B fragment order (bf16) ----------
__global__ void pack_w(const float* __restrict__ W, bf16_t* __restrict__ Bp) {
    int idx = blockIdx.x * 256 + threadIdx.x;
    if (idx >= NLC * 8 * 4 * 64 * 8) return;
    int j    = idx & 7;
    int lane = (idx >> 3) & 63;
    int kb   = (idx >> 9) & 3;
    int nt   = (idx >> 11) & 7;
    int i    = idx >> 14;
    int g = lane >> 4, c = lane & 15;
    int k = kb * 32 + ((j < 4) ? (4 * g + j) : (16 + 4 * g + (j - 4)));
    int n = nt * 16 + c;
    Bp[idx] = (bf16_t)W[i * DIMC * DIMC + n * DIMC + k];
}

// ---------- x -> bf16 compact ----------
__global__ void cvt_x(const float* __restrict__ x, unsigned* __restrict__ xb) {
    int i = blockIdx.x * 256 + threadIdx.x;
    if (i < N_NODESC * 64) {
        float2 v = ((const float2*)x)[i];
        xb[i] = pk(v.x, v.y);
    }
}

// ---------- bucketed CSR build (no global scan: fixed-capacity buckets) ----------
__global__ __launch_bounds__(256) void bscat_k(const int* __restrict__ ei,
                                               int* __restrict__ bfill,
                                               unsigned* __restrict__ ebuf) {
    __shared__ int h[256], pre[256], segb[256];
    __shared__ unsigned stage[EPB];
    __shared__ unsigned short sbb[EPB];
    int t = threadIdx.x;
    h[t] = 0;
    __syncthreads();
    int base = blockIdx.x * EPB;
    int dstv[16], srcv[16];
#pragma unroll
    for (int u = 0; u < 16; ++u) {
        int e = base + t + 256 * u;
        if (e < N_EDGESC) {
            dstv[u] = ei[N_EDGESC + e];
            srcv[u] = ei[e];
            atomicAdd(&h[dstv[u] >> 9], 1);
        } else dstv[u] = -1;
    }
    __syncthreads();
    int cnt = h[t];
    for (int off = 1; off < 256; off <<= 1) {
        int a = (t >= off) ? h[t - off] : 0;
        __syncthreads();
        h[t] += a;
        __syncthreads();
    }
    pre[t] = h[t] - cnt;
    if (t < NBUCK && cnt) segb[t] = atomicAdd(&bfill[t], cnt);
    __syncthreads();
    h[t] = pre[t];
    __syncthreads();
#pragma unroll
    for (int u = 0; u < 16; ++u) {
        if (dstv[u] >= 0) {
            int b = dstv[u] >> 9;
            int q = atomicAdd(&h[b], 1);
            stage[q] = ((unsigned)srcv[u] << 9) | (unsigned)(dstv[u] & 511);
            sbb[q] = (unsigned short)b;
        }
    }
    __syncthreads();
    int n = (base + EPB <= N_EDGESC) ? EPB : (N_EDGESC - base);
    for (int i = t; i < n; i += 256) {
        int b = sbb[i];
        ebuf[(long)b * ECAP + segb[b] + i - pre[b]] = stage[i];
    }
}

// one block per bucket: local histogram+scan -> rowse(start,end) + coalesced csr
__global__ __launch_bounds__(256) void csr_k(const unsigned* __restrict__ ebuf,
                                             const int* __restrict__ bfill,
                                             int2* __restrict__ rowse,
                                             int* __restrict__ csr) {
    __shared__ int hist[512], fill[512];
    __shared__ unsigned stage[BCAP];
    int t = threadIdx.x;
    int b = blockIdx.x;
    int cnt = bfill[b];
    long base = (long)b * ECAP;
    hist[t] = 0; hist[t + 256] = 0;
    __syncthreads();
    for (int e = t; e < cnt; e += 256)
        atomicAdd(&hist[ebuf[base + e] & 511], 1);
    __syncthreads();
    int c0 = hist[t], c1 = hist[t + 256];
    for (int off = 1; off < 512; off <<= 1) {
        int a0 = (t >= off) ? hist[t - off] : 0;
        int a1 = (t + 256 >= off) ? hist[t + 256 - off] : 0;
        __syncthreads();
        hist[t] += a0; hist[t + 256] += a1;
        __syncthreads();
    }
    int p0 = hist[t] - c0, p1 = hist[t + 256] - c1;
    fill[t] = p0; fill[t + 256] = p1;
    int n0 = b * 512;
    if (n0 + t < N_NODESC) {
        int2 r; r.x = (int)base + p0; r.y = (int)base + p0 + c0;
        rowse[n0 + t] = r;
    }
    if (n0 + t + 256 < N_NODESC) {
        int2 r; r.x = (int)base + p1; r.y = (int)base + p1 + c1;
        rowse[n0 + t + 256] = r;
    }
    __syncthreads();
    for (int e = t; e < cnt; e += 256) {
        unsigned p = ebuf[base + e];
        int q = atomicAdd(&fill[p & 511], 1);
        unsigned s = p >> 9;
        if (q < BCAP) stage[q] = s; else csr[base + q] = s;
    }
    __syncthreads();
    int m = cnt < BCAP ? cnt : BCAP;
    for (int i = t; i < m; i += 256) csr[base + i] = stage[i];
}

// ---------- degree-sort: bucket nodes by degree for balanced agg waves ----------
__global__ void dhist_k(const int2* __restrict__ rowse, int* __restrict__ dcnt) {
    int n = blockIdx.x * 256 + threadIdx.x;
    if (n < N_NODESC) {
        int2 r = rowse[n];
        int d = r.y - r.x; if (d > NDEG - 1) d = NDEG - 1;
        atomicAdd(&dcnt[d], 1);
    }
}
__global__ void dscan_k(const int* __restrict__ dcnt, int* __restrict__ dbase) {
    if (threadIdx.x == 0) {
        int run = 0;
        for (int i = 0; i < NDEG; ++i) { dbase[i] = run; run += dcnt[i]; }
    }
}
__global__ void dscat_k(const int2* __restrict__ rowse, int* __restrict__ dbase,
                        int* __restrict__ perm) {
    int n = blockIdx.x * 256 + threadIdx.x;
    if (n < N_NODESC) {
        int2 r = rowse[n];
        int d = r.y - r.x; if (d > NDEG - 1) d = NDEG - 1;
        int p = atomicAdd(&dbase[d], 1);
        perm[p] = n;
    }
}

// ---------- graph ranges from sorted batch ----------
__global__ void gptr_k(const int* __restrict__ batch, int* __restrict__ gptr) {
    int n = blockIdx.x * 256 + threadIdx.x;
    if (n >= N_NODESC) return;
    int b = batch[n];
    if (n == 0) for (int g = 0; g <= b; ++g) gptr[g] = 0;
    if (n == N_NODESC - 1) {
        for (int g = b + 1; g <= N_GRAPHSC; ++g) gptr[g] = N_NODESC;
    } else {
        int b2 = batch[n + 1];
        for (int g = b + 1; g <= b2; ++g) gptr[g] = n + 1;
    }
}

// ---------- aggregation (bf16 uint4 gather, 4 deg-matched nodes/wave, BN folded) ----------
// h_pre = sc * ((1+eps)*self + sum_nb) + (deg+1+eps) * sh   [sc=1,sh=0 for layer 0]
__global__ __launch_bounds__(256) void agg_k(const unsigned* __restrict__ src,
                                             const float* __restrict__ epsp, int layer,
                                             const float* __restrict__ scale,
                                             const float* __restrict__ shift,
                                             const int2* __restrict__ rowse,
                                             const int* __restrict__ csr,
                                             const int* __restrict__ perm,
                                             unsigned* __restrict__ hpre) {
    int t = threadIdx.x;
    int wave = t >> 6, lane = t & 63;
    int h = lane >> 4;       // which node of the 4
    int c = lane & 15;       // uint4 chunk (16 B) within 256 B row
    int n = perm[blockIdx.x * 16 + wave * 4 + h];
    const uint4* rows = (const uint4*)src;
    float eps = epsp[layer];
    int2 re = rowse[n];
    int jb = re.x, je = re.y;
    uint4 us = rows[(long)n * 16 + c];
    float a0 = 0.f, a1 = 0.f, a2 = 0.f, a3 = 0.f;
    float a4 = 0.f, a5 = 0.f, a6 = 0.f, a7 = 0.f;
    int j = jb;
    for (; j + 8 <= je; j += 8) {
        uint4 u0 = rows[(long)csr[j] * 16 + c];
        uint4 u1 = rows[(long)csr[j + 1] * 16 + c];
        uint4 u2 = rows[(long)csr[j + 2] * 16 + c];
        uint4 u3 = rows[(long)csr[j + 3] * 16 + c];
        uint4 u4 = rows[(long)csr[j + 4] * 16 + c];
        uint4 u5 = rows[(long)csr[j + 5] * 16 + c];
        uint4 u6 = rows[(long)csr[j + 6] * 16 + c];
        uint4 u7 = rows[(long)csr[j + 7] * 16 + c];
        a0 += (bl(u0.x) + bl(u1.x) + bl(u2.x) + bl(u3.x))
            + (bl(u4.x) + bl(u5.x) + bl(u6.x) + bl(u7.x));
        a1 += (bh(u0.x) + bh(u1.x) + bh(u2.x) + bh(u3.x))
            + (bh(u4.x) + bh(u5.x) + bh(u6.x) + bh(u7.x));
        a2 += (bl(u0.y) + bl(u1.y) + bl(u2.y) + bl(u3.y))
            + (bl(u4.y) + bl(u5.y) + bl(u6.y) + bl(u7.y));
        a3 += (bh(u0.y) + bh(u1.y) + bh(u2.y) + bh(u3.y))
            + (bh(u4.y) + bh(u5.y) + bh(u6.y) + bh(u7.y));
        a4 += (bl(u0.z) + bl(u1.z) + bl(u2.z) + bl(u3.z))
            + (bl(u4.z) + bl(u5.z) + bl(u6.z) + bl(u7.z));
        a5 += (bh(u0.z) + bh(u1.z) + bh(u2.z) + bh(u3.z))
            + (bh(u4.z) + bh(u5.z) + bh(u6.z) + bh(u7.z));
        a6 += (bl(u0.w) + bl(u1.w) + bl(u2.w) + bl(u3.w))
            + (bl(u4.w) + bl(u5.w) + bl(u6.w) + bl(u7.w));
        a7 += (bh(u0.w) + bh(u1.w) + bh(u2.w) + bh(u3.w))
            + (bh(u4.w) + bh(u5.w) + bh(u6.w) + bh(u7.w));
    }
    for (; j + 4 <= je; j += 4) {
        uint4 u0 = rows[(long)csr[j] * 16 + c];
        uint4 u1 = rows[(long)csr[j + 1] * 16 + c];
        uint4 u2 = rows[(long)csr[j + 2] * 16 + c];
        uint4 u3 = rows[(long)csr[j + 3] * 16 + c];
        a0 += bl(u0.x) + bl(u1.x) + bl(u2.x) + bl(u3.x);
        a1 += bh(u0.x) + bh(u1.x) + bh(u2.x) + bh(u3.x);
        a2 += bl(u0.y) + bl(u1.y) + bl(u2.y) + bl(u3.y);
        a3 += bh(u0.y) + bh(u1.y) + bh(u2.y) + bh(u3.y);
        a4 += bl(u0.z) + bl(u1.z) + bl(u2.z) + bl(u3.z);
        a5 += bh(u0.z) + bh(u1.z) + bh(u2.z) + bh(u3.z);
        a6 += bl(u0.w) + bl(u1.w) + bl(u2.w) + bl(u3.w);
        a7 += bh(u0.w) + bh(u1.w) + bh(u2.w) + bh(u3.w);
    }
    for (; j < je; ++j) {
        uint4 u = rows[(long)csr[j] * 16 + c];
        a0 += bl(u.x); a1 += bh(u.x); a2 += bl(u.y); a3 += bh(u.y);
        a4 += bl(u.z); a5 += bh(u.z); a6 += bl(u.w); a7 += bh(u.w);
    }
    float se = 1.f + eps;
    float t0 = se * bl(us.x) + a0, t1 = se * bh(us.x) + a1;
    float t2 = se * bl(us.y) + a2, t3 = se * bh(us.y) + a3;
    float t4 = se * bl(us.z) + a4, t5 = se * bh(us.z) + a5;
    float t6 = se * bl(us.w) + a6, t7 = se * bh(us.w) + a7;
    uint4 o;
    if (scale) {
        float cdeg = (float)(je - jb) + se;
        int f = 8 * c;
        o.x = pk(scale[f] * t0 + cdeg * shift[f],
                 scale[f + 1] * t1 + cdeg * shift[f + 1]);
        o.y = pk(scale[f + 2] * t2 + cdeg * shift[f + 2],
                 scale[f + 3] * t3 + cdeg * shift[f + 3]);
        o.z = pk(scale[f + 4] * t4 + cdeg * shift[f + 4],
                 scale[f + 5] * t5 + cdeg * shift[f + 5]);
        o.w = pk(scale[f + 6] * t6 + cdeg * shift[f + 6],
                 scale[f + 7] * t7 + cdeg * shift[f + 7]);
    } else {
        o.x = pk(t0, t1); o.y = pk(t2, t3); o.z = pk(t4, t5); o.w = pk(t6, t7);
    }
    ((uint4*)hpre)[(long)n * 16 + c] = o;
}

// ---------- GEMM: relu(h_pre @ W^T + b) -> hu (bf16, uint2 packed stores) ----------
__global__ __launch_bounds__(256) void gemm_k(const bf16_t* __restrict__ hb,
                                              const bf16_t* __restrict__ Bp,
                                              const float* __restrict__ bias,
                                              bf16_t* __restrict__ hu,
                                              float* __restrict__ bsum,
                                              float* __restrict__ bsq) {
    __shared__ bf16_t Bl[8 * 4 * 64 * 8];  // 32 KiB
    __shared__ float lsum[DIMC], lsq[DIMC];
    int t = threadIdx.x;
    {
        const int4* s = (const int4*)Bp;
        int4* dl = (int4*)Bl;
#pragma unroll
        for (int u = 0; u < 8; ++u) dl[t + 256 * u] = s[t + 256 * u];
    }
    if (t < DIMC) { lsum[t] = 0.f; lsq[t] = 0.f; }
    __syncthreads();
    int wave = t >> 6, lane = t & 63;
    int tile = blockIdx.x * 4 + wave;
    int col = lane & 15, g = lane >> 4;
    if (tile < N_NODESC / 16) {
        int row0 = tile * 16;
        const bf16_t* arow = hb + (long)(row0 + col) * DIMC;
        bf16x8 a[4];
#pragma unroll
        for (int kb = 0; kb < 4; ++kb) {
            bf16x4 lo = *(const bf16x4*)(arow + kb * 32 + 4 * g);
            bf16x4 hi = *(const bf16x4*)(arow + kb * 32 + 16 + 4 * g);
            bf16x8 av;
            av[0] = lo[0]; av[1] = lo[1]; av[2] = lo[2]; av[3] = lo[3];
            av[4] = hi[0]; av[5] = hi[1]; av[6] = hi[2]; av[7] = hi[3];
            a[kb] = av;
        }
#pragma unroll
        for (int nt = 0; nt < 8; ++nt) {
            f32x4 acc = {0.f, 0.f, 0.f, 0.f};
#pragma unroll
            for (int kb = 0; kb < 4; ++kb) {
                bf16x8 bv = *(const bf16x8*)&Bl[((nt * 4 + kb) * 64 + lane) * 8];
                acc = __builtin_amdgcn_mfma_f32_16x16x32_bf16(a[kb], bv, acc, 0, 0, 0);
            }
            int f = nt * 16 + col;
            float bi = bias[f];
            float ss = 0.f, sq = 0.f;
#pragma unroll
            for (int r = 0; r < 4; ++r) {
                float v = fmaxf(acc[r] + bi, 0.f);
                float vf = (float)(bf16_t)v;
                ss += vf; sq += vf * vf;
                float vo = __shfl_xor(vf, 1);
                unsigned u = pk(vf, vo);
                unsigned u2 = (unsigned)__shfl_xor((int)u, 2);
                if ((col & 3) == 0) {
                    uint2 st; st.x = u; st.y = u2;
                    *(uint2*)&hu[(long)(row0 + g * 4 + r) * DIMC + nt * 16 + col] = st;
                }
            }
            ss += __shfl_xor(ss, 16);
            ss += __shfl_xor(ss, 32);
            sq += __shfl_xor(sq, 16);
            sq += __shfl_xor(sq, 32);
            if (g == 0) { atomicAdd(&lsum[f], ss); atomicAdd(&lsq[f], sq); }
        }
    }
    __syncthreads();
    if (t < DIMC) atomicAdd(&bsum[t], lsum[t]);
    else if (t < 2 * DIMC) atomicAdd(&bsq[t - DIMC], lsq[t - DIMC]);
}

// ---------- fused BN-param + BN-apply (z_cat) + global_add_pool (g_cat) ----------
__global__ __launch_bounds__(512) void fuse_k(const unsigned* __restrict__ hu32,
                                              const float* __restrict__ bsum,
                                              const float* __restrict__ bsq,
                                              const float* __restrict__ gamma,
                                              const float* __restrict__ beta,
                                              float* __restrict__ scaleOut,
                                              float* __restrict__ shiftOut,
                                              const int* __restrict__ gptr,
                                              float* __restrict__ out,
                                              float* __restrict__ gout, int layerOff) {
    __shared__ float red[8][DIMC];
    __shared__ float sc[DIMC], sh[DIMC];
    int g = blockIdx.x, t = threadIdx.x;
    if (t < DIMC) {
        float mu = bsum[t] * (1.0f / N_NODESC);
        float var = bsq[t] * (1.0f / N_NODESC) - mu * mu;
        float s = rsqrtf(var + 1e-5f) * gamma[t];
        float b = beta[t] - mu * s;
        sc[t] = s; sh[t] = b;
        if (g == 0) { scaleOut[t] = s; shiftOut[t] = b; }
    }
    __syncthreads();
    int q = t >> 6, lane = t & 63;
    int s0i = gptr[g], e0i = gptr[g + 1];
    float sc0 = sc[2 * lane], sc1 = sc[2 * lane + 1];
    float sh0 = sh[2 * lane], sh1 = sh[2 * lane + 1];
    float p0 = 0.f, p1 = 0.f;
    for (int n = s0i + q; n < e0i; n += 8) {
        unsigned u = hu32[(long)n * 64 + lane];
        float v0 = bl(u), v1 = bh(u);
        p0 += v0; p1 += v1;
        float2 w;
        w.x = sc0 * v0 + sh0;
        w.y = sc1 * v1 + sh1;
        *(float2*)&out[(long)n * (3 * DIMC) + layerOff + 2 * lane] = w;
    }
    red[q][2 * lane] = p0;
    red[q][2 * lane + 1] = p1;
    __syncthreads();
    if (t < DIMC) {
        float sum = 0.f;
#pragma unroll
        for (int k = 0; k < 8; ++k) sum += red[k][t];
        float cnt = (float)(e0i - s0i);
        gout[(long)g * (3 * DIMC) + layerOff + t] = sc[t] * sum + cnt * sh[t];
    }
}

extern "C" void kernel_launch(void* const* d_in, const int* in_sizes, int n_in,
                              void* d_out, int out_size, void* d_ws, size_t ws_size,
                              hipStream_t stream) {
    const float* x     = (const float*)d_in[0];
    const float* W     = (const float*)d_in[1];
    const float* b     = (const float*)d_in[2];
    const float* eps_p = (const float*)d_in[3];
    const float* gamma = (const float*)d_in[4];
    const float* beta  = (const float*)d_in[5];
    const int*   ei    = (const int*)d_in[6];
    const int*   batch = (const int*)d_in[7];
    float* out = (float*)d_out;
    float* gout = out + (size_t)N_NODESC * 3 * DIMC;
    char* ws = (char*)d_ws;

    size_t off = 0;
    auto alloc = [&](size_t bytes) {
        void* p = ws + off;
        off = (off + bytes + 255) & ~(size_t)255;
        return p;
    };
    // zero-region: bfill + bsum + bsq + dcnt contiguous -> single memset
    int*      bfill  = (int*)alloc(256 * sizeof(int));
    float*    bsum   = (float*)alloc(NLC * DIMC * sizeof(float));
    float*    bsq    = (float*)alloc(NLC * DIMC * sizeof(float));
    int*      dcnt   = (int*)alloc(NDEG * sizeof(int));
    size_t    zbytes = off;
    int2*     rowse  = (int2*)alloc((size_t)N_NODESC * sizeof(int2));
    int*      csr    = (int*)alloc((size_t)NBUCK * ECAP * sizeof(int));
    // xb aliases ebuf: ebuf (8 MB) is dead once csr_k completes; cvt_x runs after.
    unsigned* xb     = (unsigned*)alloc((size_t)N_NODESC * 64 * 4);
    unsigned* ebuf   = xb;
    unsigned* hpre   = (unsigned*)alloc((size_t)N_NODESC * 64 * 4);
    unsigned* hu     = (unsigned*)alloc((size_t)N_NODESC * 64 * 4);
    bf16_t*   Bp     = (bf16_t*)alloc((size_t)NLC * DIMC * DIMC * 2);
    float*    scale  = (float*)alloc(NLC * DIMC * sizeof(float));
    float*    shift  = (float*)alloc(NLC * DIMC * sizeof(float));
    int*      dbase  = (int*)alloc(NDEG * sizeof(int));
    int*      perm   = (int*)alloc((size_t)N_NODESC * sizeof(int));
    int*      gptr   = (int*)alloc((N_GRAPHSC + 1) * sizeof(int));

    hipMemsetAsync(ws, 0, zbytes, stream);

    int nEB = (N_EDGESC + EPB - 1) / EPB;
    bscat_k<<<nEB, 256, 0, stream>>>(ei, bfill, ebuf);
    csr_k<<<NBUCK, 256, 0, stream>>>(ebuf, bfill, rowse, csr);
    dhist_k<<<(N_NODESC + 255) / 256, 256, 0, stream>>>(rowse, dcnt);
    dscan_k<<<1, 64, 0, stream>>>(dcnt, dbase);
    dscat_k<<<(N_NODESC + 255) / 256, 256, 0, stream>>>(rowse, dbase, perm);
    // ebuf dead from here; xb reuses its space.
    pack_w<<<192, 256, 0, stream>>>(W, Bp);
    cvt_x<<<N_NODESC * 64 / 256, 256, 0, stream>>>(x, xb);
    gptr_k<<<(N_NODESC + 255) / 256, 256, 0, stream>>>(batch, gptr);

    for (int i = 0; i < NLC; ++i) {
        const unsigned* src = (i == 0) ? xb : hu;
        const float* scA = (i == 0) ? nullptr : (scale + (size_t)(i - 1) * DIMC);
        const float* shA = (i == 0) ? nullptr : (shift + (size_t)(i - 1) * DIMC);
        agg_k<<<N_NODESC / 16, 256, 0, stream>>>(src, eps_p, i, scA, shA, rowse, csr,
                                                 perm, hpre);
        gemm_k<<<(N_NODESC / 16 + 3) / 4, 256, 0, stream>>>(
            (const bf16_t*)hpre, Bp + (size_t)i * DIMC * DIMC, b + (size_t)i * DIMC,
            (bf16_t*)hu, bsum + (size_t)i * DIMC, bsq + (size_t)i * DIMC);
        fuse_k<<<N_GRAPHSC, 512, 0, stream>>>(
            hu, bsum + (size_t)i * DIMC, bsq + (size_t)i * DIMC,
            gamma + (size_t)i * DIMC, beta + (size_t)i * DIMC,
            scale + (size_t)i * DIMC, shift + (size_t)i * DIMC,
            gptr, out, gout, i * DIMC);
    }
}

// Round 11
// 479.537 us; speedup vs baseline: 2.0709x; 2.0709x over previous
//
#include <hip/hip_runtime.h>

#define N_NODESC 100000
#define N_EDGESC 1600000
#define N_GRAPHSC 512
#define DIMC 128
#define NLC 3
#define NBUCK 196      // ceil(100000/512)
#define EPB 4096       // edges per block in bucket scatter
#define ECAP 10240     // fixed per-bucket capacity (mean 8192, sigma~90)
#define BCAP 12288     // LDS staging capacity per bucket
#define NDEG 64        // degree buckets for load-balance sort

typedef __bf16 bf16_t;
typedef __bf16 bf16x2 __attribute__((ext_vector_type(2)));
typedef __bf16 bf16x4 __attribute__((ext_vector_type(4)));
typedef __bf16 bf16x8 __attribute__((ext_vector_type(8)));
typedef float f32x4 __attribute__((ext_vector_type(4)));

__device__ inline float bl(unsigned u) { union { unsigned x; float f; } c; c.x = u << 16; return c.f; }
__device__ inline float bh(unsigned u) { union { unsigned x; float f; } c; c.x = u & 0xffff0000u; return c.f; }
__device__ inline unsigned pk(float a, float b) {
    bf16x2 p; p[0] = (bf16_t)a; p[1] = (bf16_t)b;
    unsigned u; __builtin_memcpy(&u, &p, 4); return u;
}

// ---------- pack W^T (f32) into MFMA-B fragment order (bf16) ----------
__global__ void pack_w(const float* __restrict__ W, bf16_t* __restrict__ Bp) {
    int idx = blockIdx.x * 256 + threadIdx.x;
    if (idx >= NLC * 8 * 4 * 64 * 8) return;
    int j    = idx & 7;
    int lane = (idx >> 3) & 63;
    int kb   = (idx >> 9) & 3;
    int nt   = (idx >> 11) & 7;
    int i    = idx >> 14;
    int g = lane >> 4, c = lane & 15;
    int k = kb * 32 + ((j < 4) ? (4 * g + j) : (16 + 4 * g + (j - 4)));
    int n = nt * 16 + c;
    Bp[idx] = (bf16_t)W[i * DIMC * DIMC + n * DIMC + k];
}

// ---------- x -> bf16 compact ----------
__global__ void cvt_x(const float* __restrict__ x, unsigned* __restrict__ xb) {
    int i = blockIdx.x * 256 + threadIdx.x;
    if (i < N_NODESC * 64) {
        float2 v = ((const float2*)x)[i];
        xb[i] = pk(v.x, v.y);
    }
}

// ---------- bucketed CSR build (no global scan: fixed-capacity buckets) ----------
__global__ __launch_bounds__(256) void bscat_k(const int* __restrict__ ei,
                                               int* __restrict__ bfill,
                                               unsigned* __restrict__ ebuf) {
    __shared__ int h[256], pre[256], segb[256];
    __shared__ unsigned stage[EPB];
    __shared__ unsigned short sbb[EPB];
    int t = threadIdx.x;
    h[t] = 0;
    __syncthreads();
    int base = blockIdx.x * EPB;
    int dstv[16], srcv[16];
#pragma unroll
    for (int u = 0; u < 16; ++u) {
        int e = base + t + 256 * u;
        if (e < N_EDGESC) {
            dstv[u] = ei[N_EDGESC + e];
            srcv[u] = ei[e];
            atomicAdd(&h[dstv[u] >> 9], 1);
        } else dstv[u] = -1;
    }
    __syncthreads();
    int cnt = h[t];
    for (int off = 1; off < 256; off <<= 1) {
        int a = (t >= off) ? h[t - off] : 0;
        __syncthreads();
        h[t] += a;
        __syncthreads();
    }
    pre[t] = h[t] - cnt;
    if (t < NBUCK && cnt) segb[t] = atomicAdd(&bfill[t], cnt);
    __syncthreads();
    h[t] = pre[t];
    __syncthreads();
#pragma unroll
    for (int u = 0; u < 16; ++u) {
        if (dstv[u] >= 0) {
            int b = dstv[u] >> 9;
            int q = atomicAdd(&h[b], 1);
            stage[q] = ((unsigned)srcv[u] << 9) | (unsigned)(dstv[u] & 511);
            sbb[q] = (unsigned short)b;
        }
    }
    __syncthreads();
    int n = (base + EPB <= N_EDGESC) ? EPB : (N_EDGESC - base);
    for (int i = t; i < n; i += 256) {
        int b = sbb[i];
        ebuf[(long)b * ECAP + segb[b] + i - pre[b]] = stage[i];
    }
}

// one block per bucket: local histogram+scan -> rowse(start,end) + coalesced csr
__global__ __launch_bounds__(256) void csr_k(const unsigned* __restrict__ ebuf,
                                             const int* __restrict__ bfill,
                                             int2* __restrict__ rowse,
                                             int* __restrict__ csr) {
    __shared__ int hist[512], fill[512];
    __shared__ unsigned stage[BCAP];
    int t = threadIdx.x;
    int b = blockIdx.x;
    int cnt = bfill[b];
    long base = (long)b * ECAP;
    hist[t] = 0; hist[t + 256] = 0;
    __syncthreads();
    for (int e = t; e < cnt; e += 256)
        atomicAdd(&hist[ebuf[base + e] & 511], 1);
    __syncthreads();
    int c0 = hist[t], c1 = hist[t + 256];
    for (int off = 1; off < 512; off <<= 1) {
        int a0 = (t >= off) ? hist[t - off] : 0;
        int a1 = (t + 256 >= off) ? hist[t + 256 - off] : 0;
        __syncthreads();
        hist[t] += a0; hist[t + 256] += a1;
        __syncthreads();
    }
    int p0 = hist[t] - c0, p1 = hist[t + 256] - c1;
    fill[t] = p0; fill[t + 256] = p1;
    int n0 = b * 512;
    if (n0 + t < N_NODESC) {
        int2 r; r.x = (int)base + p0; r.y = (int)base + p0 + c0;
        rowse[n0 + t] = r;
    }
    if (n0 + t + 256 < N_NODESC) {
        int2 r; r.x = (int)base + p1; r.y = (int)base + p1 + c1;
        rowse[n0 + t + 256] = r;
    }
    __syncthreads();
    for (int e = t; e < cnt; e += 256) {
        unsigned p = ebuf[base + e];
        int q = atomicAdd(&fill[p & 511], 1);
        unsigned s = p >> 9;
        if (q < BCAP) stage[q] = s; else csr[base + q] = s;
    }
    __syncthreads();
    int m = cnt < BCAP ? cnt : BCAP;
    for (int i = t; i < m; i += 256) csr[base + i] = stage[i];
}

// ---------- degree-sort (LDS-aggregated histograms; ~25K global atomics total) ----------
__global__ __launch_bounds__(256) void dhist_k(const int2* __restrict__ rowse,
                                               int* __restrict__ dcnt) {
    __shared__ int h[NDEG];
    int t = threadIdx.x;
    if (t < NDEG) h[t] = 0;
    __syncthreads();
    int n = blockIdx.x * 256 + t;
    if (n < N_NODESC) {
        int2 r = rowse[n];
        int d = r.y - r.x; if (d > NDEG - 1) d = NDEG - 1;
        atomicAdd(&h[d], 1);
    }
    __syncthreads();
    if (t < NDEG && h[t]) atomicAdd(&dcnt[t], h[t]);
}
__global__ void dscan_k(const int* __restrict__ dcnt, int* __restrict__ dbase) {
    if (threadIdx.x == 0) {
        int run = 0;
        for (int i = 0; i < NDEG; ++i) { dbase[i] = run; run += dcnt[i]; }
    }
}
__global__ __launch_bounds__(256) void dscat_k(const int2* __restrict__ rowse,
                                               int* __restrict__ dbase,
                                               int* __restrict__ perm) {
    __shared__ int h[NDEG], segb[NDEG];
    int t = threadIdx.x;
    if (t < NDEG) h[t] = 0;
    __syncthreads();
    int n = blockIdx.x * 256 + t;
    int d = -1, r = 0;
    if (n < N_NODESC) {
        int2 re = rowse[n];
        d = re.y - re.x; if (d > NDEG - 1) d = NDEG - 1;
        r = atomicAdd(&h[d], 1);          // local rank within block
    }
    __syncthreads();
    if (t < NDEG && h[t]) segb[t] = atomicAdd(&dbase[t], h[t]);  // 64 atomics/block
    __syncthreads();
    if (d >= 0) perm[segb[d] + r] = n;
}

// ---------- graph ranges from sorted batch ----------
__global__ void gptr_k(const int* __restrict__ batch, int* __restrict__ gptr) {
    int n = blockIdx.x * 256 + threadIdx.x;
    if (n >= N_NODESC) return;
    int b = batch[n];
    if (n == 0) for (int g = 0; g <= b; ++g) gptr[g] = 0;
    if (n == N_NODESC - 1) {
        for (int g = b + 1; g <= N_GRAPHSC; ++g) gptr[g] = N_NODESC;
    } else {
        int b2 = batch[n + 1];
        for (int g = b + 1; g <= b2; ++g) gptr[g] = n + 1;
    }
}

// ---------- aggregation (bf16 uint4 gather, 4 deg-matched nodes/wave, BN folded) ----------
// h_pre = sc * ((1+eps)*self + sum_nb) + (deg+1+eps) * sh   [sc=1,sh=0 for layer 0]
__global__ __launch_bounds__(256) void agg_k(const unsigned* __restrict__ src,
                                             const float* __restrict__ epsp, int layer,
                                             const float* __restrict__ scale,
                                             const float* __restrict__ shift,
                                             const int2* __restrict__ rowse,
                                             const int* __restrict__ csr,
                                             const int* __restrict__ perm,
                                             unsigned* __restrict__ hpre) {
    int t = threadIdx.x;
    int wave = t >> 6, lane = t & 63;
    int h = lane >> 4;       // which node of the 4
    int c = lane & 15;       // uint4 chunk (16 B) within 256 B row
    int n = perm[blockIdx.x * 16 + wave * 4 + h];
    const uint4* rows = (const uint4*)src;
    float eps = epsp[layer];
    int2 re = rowse[n];
    int jb = re.x, je = re.y;
    uint4 us = rows[(long)n * 16 + c];
    float a0 = 0.f, a1 = 0.f, a2 = 0.f, a3 = 0.f;
    float a4 = 0.f, a5 = 0.f, a6 = 0.f, a7 = 0.f;
    int j = jb;
    for (; j + 8 <= je; j += 8) {
        uint4 u0 = rows[(long)csr[j] * 16 + c];
        uint4 u1 = rows[(long)csr[j + 1] * 16 + c];
        uint4 u2 = rows[(long)csr[j + 2] * 16 + c];
        uint4 u3 = rows[(long)csr[j + 3] * 16 + c];
        uint4 u4 = rows[(long)csr[j + 4] * 16 + c];
        uint4 u5 = rows[(long)csr[j + 5] * 16 + c];
        uint4 u6 = rows[(long)csr[j + 6] * 16 + c];
        uint4 u7 = rows[(long)csr[j + 7] * 16 + c];
        a0 += (bl(u0.x) + bl(u1.x) + bl(u2.x) + bl(u3.x))
            + (bl(u4.x) + bl(u5.x) + bl(u6.x) + bl(u7.x));
        a1 += (bh(u0.x) + bh(u1.x) + bh(u2.x) + bh(u3.x))
            + (bh(u4.x) + bh(u5.x) + bh(u6.x) + bh(u7.x));
        a2 += (bl(u0.y) + bl(u1.y) + bl(u2.y) + bl(u3.y))
            + (bl(u4.y) + bl(u5.y) + bl(u6.y) + bl(u7.y));
        a3 += (bh(u0.y) + bh(u1.y) + bh(u2.y) + bh(u3.y))
            + (bh(u4.y) + bh(u5.y) + bh(u6.y) + bh(u7.y));
        a4 += (bl(u0.z) + bl(u1.z) + bl(u2.z) + bl(u3.z))
            + (bl(u4.z) + bl(u5.z) + bl(u6.z) + bl(u7.z));
        a5 += (bh(u0.z) + bh(u1.z) + bh(u2.z) + bh(u3.z))
            + (bh(u4.z) + bh(u5.z) + bh(u6.z) + bh(u7.z));
        a6 += (bl(u0.w) + bl(u1.w) + bl(u2.w) + bl(u3.w))
            + (bl(u4.w) + bl(u5.w) + bl(u6.w) + bl(u7.w));
        a7 += (bh(u0.w) + bh(u1.w) + bh(u2.w) + bh(u3.w))
            + (bh(u4.w) + bh(u5.w) + bh(u6.w) + bh(u7.w));
    }
    for (; j + 4 <= je; j += 4) {
        uint4 u0 = rows[(long)csr[j] * 16 + c];
        uint4 u1 = rows[(long)csr[j + 1] * 16 + c];
        uint4 u2 = rows[(long)csr[j + 2] * 16 + c];
        uint4 u3 = rows[(long)csr[j + 3] * 16 + c];
        a0 += bl(u0.x) + bl(u1.x) + bl(u2.x) + bl(u3.x);
        a1 += bh(u0.x) + bh(u1.x) + bh(u2.x) + bh(u3.x);
        a2 += bl(u0.y) + bl(u1.y) + bl(u2.y) + bl(u3.y);
        a3 += bh(u0.y) + bh(u1.y) + bh(u2.y) + bh(u3.y);
        a4 += bl(u0.z) + bl(u1.z) + bl(u2.z) + bl(u3.z);
        a5 += bh(u0.z) + bh(u1.z) + bh(u2.z) + bh(u3.z);
        a6 += bl(u0.w) + bl(u1.w) + bl(u2.w) + bl(u3.w);
        a7 += bh(u0.w) + bh(u1.w) + bh(u2.w) + bh(u3.w);
    }
    for (; j < je; ++j) {
        uint4 u = rows[(long)csr[j] * 16 + c];
        a0 += bl(u.x); a1 += bh(u.x); a2 += bl(u.y); a3 += bh(u.y);
        a4 += bl(u.z); a5 += bh(u.z); a6 += bl(u.w); a7 += bh(u.w);
    }
    float se = 1.f + eps;
    float t0 = se * bl(us.x) + a0, t1 = se * bh(us.x) + a1;
    float t2 = se * bl(us.y) + a2, t3 = se * bh(us.y) + a3;
    float t4 = se * bl(us.z) + a4, t5 = se * bh(us.z) + a5;
    float t6 = se * bl(us.w) + a6, t7 = se * bh(us.w) + a7;
    uint4 o;
    if (scale) {
        float cdeg = (float)(je - jb) + se;
        int f = 8 * c;
        o.x = pk(scale[f] * t0 + cdeg * shift[f],
                 scale[f + 1] * t1 + cdeg * shift[f + 1]);
        o.y = pk(scale[f + 2] * t2 + cdeg * shift[f + 2],
                 scale[f + 3] * t3 + cdeg * shift[f + 3]);
        o.z = pk(scale[f + 4] * t4 + cdeg * shift[f + 4],
                 scale[f + 5] * t5 + cdeg * shift[f + 5]);
        o.w = pk(scale[f + 6] * t6 + cdeg * shift[f + 6],
                 scale[f + 7] * t7 + cdeg * shift[f + 7]);
    } else {
        o.x = pk(t0, t1); o.y = pk(t2, t3); o.z = pk(t4, t5); o.w = pk(t6, t7);
    }
    ((uint4*)hpre)[(long)n * 16 + c] = o;
}

// ---------- GEMM: relu(h_pre @ W^T + b) -> hu (bf16, uint2 packed stores) ----------
__global__ __launch_bounds__(256) void gemm_k(const bf16_t* __restrict__ hb,
                                              const bf16_t* __restrict__ Bp,
                                              const float* __restrict__ bias,
                                              bf16_t* __restrict__ hu,
                                              float* __restrict__ bsum,
                                              float* __restrict__ bsq) {
    __shared__ bf16_t Bl[8 * 4 * 64 * 8];  // 32 KiB
    __shared__ float lsum[DIMC], lsq[DIMC];
    int t = threadIdx.x;
    {
        const int4* s = (const int4*)Bp;
        int4* dl = (int4*)Bl;
#pragma unroll
        for (int u = 0; u < 8; ++u) dl[t + 256 * u] = s[t + 256 * u];
    }
    if (t < DIMC) { lsum[t] = 0.f; lsq[t] = 0.f; }
    __syncthreads();
    int wave = t >> 6, lane = t & 63;
    int tile = blockIdx.x * 4 + wave;
    int col = lane & 15, g = lane >> 4;
    if (tile < N_NODESC / 16) {
        int row0 = tile * 16;
        const bf16_t* arow = hb + (long)(row0 + col) * DIMC;
        bf16x8 a[4];
#pragma unroll
        for (int kb = 0; kb < 4; ++kb) {
            bf16x4 lo = *(const bf16x4*)(arow + kb * 32 + 4 * g);
            bf16x4 hi = *(const bf16x4*)(arow + kb * 32 + 16 + 4 * g);
            bf16x8 av;
            av[0] = lo[0]; av[1] = lo[1]; av[2] = lo[2]; av[3] = lo[3];
            av[4] = hi[0]; av[5] = hi[1]; av[6] = hi[2]; av[7] = hi[3];
            a[kb] = av;
        }
#pragma unroll
        for (int nt = 0; nt < 8; ++nt) {
            f32x4 acc = {0.f, 0.f, 0.f, 0.f};
#pragma unroll
            for (int kb = 0; kb < 4; ++kb) {
                bf16x8 bv = *(const bf16x8*)&Bl[((nt * 4 + kb) * 64 + lane) * 8];
                acc = __builtin_amdgcn_mfma_f32_16x16x32_bf16(a[kb], bv, acc, 0, 0, 0);
            }
            int f = nt * 16 + col;
            float bi = bias[f];
            float ss = 0.f, sq = 0.f;
#pragma unroll
            for (int r = 0; r < 4; ++r) {
                float v = fmaxf(acc[r] + bi, 0.f);
                float vf = (float)(bf16_t)v;
                ss += vf; sq += vf * vf;
                float vo = __shfl_xor(vf, 1);
                unsigned u = pk(vf, vo);
                unsigned u2 = (unsigned)__shfl_xor((int)u, 2);
                if ((col & 3) == 0) {
                    uint2 st; st.x = u; st.y = u2;
                    *(uint2*)&hu[(long)(row0 + g * 4 + r) * DIMC + nt * 16 + col] = st;
                }
            }
            ss += __shfl_xor(ss, 16);
            ss += __shfl_xor(ss, 32);
            sq += __shfl_xor(sq, 16);
            sq += __shfl_xor(sq, 32);
            if (g == 0) { atomicAdd(&lsum[f], ss); atomicAdd(&lsq[f], sq); }
        }
    }
    __syncthreads();
    if (t < DIMC) atomicAdd(&bsum[t], lsum[t]);
    else if (t < 2 * DIMC) atomicAdd(&bsq[t - DIMC], lsq[t - DIMC]);
}

// ---------- fused BN-param + BN-apply (z_cat) + global_add_pool (g_cat) ----------
__global__ __launch_bounds__(512) void fuse_k(const unsigned* __restrict__ hu32,
                                              const float* __restrict__ bsum,
                                              const float* __restrict__ bsq,
                                              const float* __restrict__ gamma,
                                              const float* __restrict__ beta,
                                              float* __restrict__ scaleOut,
                                              float* __restrict__ shiftOut,
                                              const int* __restrict__ gptr,
                                              float* __restrict__ out,
                                              float* __restrict__ gout, int layerOff) {
    __shared__ float red[8][DIMC];
    __shared__ float sc[DIMC], sh[DIMC];
    int g = blockIdx.x, t = threadIdx.x;
    if (t < DIMC) {
        float mu = bsum[t] * (1.0f / N_NODESC);
        float var = bsq[t] * (1.0f / N_NODESC) - mu * mu;
        float s = rsqrtf(var + 1e-5f) * gamma[t];
        float b = beta[t] - mu * s;
        sc[t] = s; sh[t] = b;
        if (g == 0) { scaleOut[t] = s; shiftOut[t] = b; }
    }
    __syncthreads();
    int q = t >> 6, lane = t & 63;
    int s0i = gptr[g], e0i = gptr[g + 1];
    float sc0 = sc[2 * lane], sc1 = sc[2 * lane + 1];
    float sh0 = sh[2 * lane], sh1 = sh[2 * lane + 1];
    float p0 = 0.f, p1 = 0.f;
    for (int n = s0i + q; n < e0i; n += 8) {
        unsigned u = hu32[(long)n * 64 + lane];
        float v0 = bl(u), v1 = bh(u);
        p0 += v0; p1 += v1;
        float2 w;
        w.x = sc0 * v0 + sh0;
        w.y = sc1 * v1 + sh1;
        *(float2*)&out[(long)n * (3 * DIMC) + layerOff + 2 * lane] = w;
    }
    red[q][2 * lane] = p0;
    red[q][2 * lane + 1] = p1;
    __syncthreads();
    if (t < DIMC) {
        float sum = 0.f;
#pragma unroll
        for (int k = 0; k < 8; ++k) sum += red[k][t];
        float cnt = (float)(e0i - s0i);
        gout[(long)g * (3 * DIMC) + layerOff + t] = sc[t] * sum + cnt * sh[t];
    }
}

extern "C" void kernel_launch(void* const* d_in, const int* in_sizes, int n_in,
                              void* d_out, int out_size, void* d_ws, size_t ws_size,
                              hipStream_t stream) {
    const float* x     = (const float*)d_in[0];
    const float* W     = (const float*)d_in[1];
    const float* b     = (const float*)d_in[2];
    const float* eps_p = (const float*)d_in[3];
    const float* gamma = (const float*)d_in[4];
    const float* beta  = (const float*)d_in[5];
    const int*   ei    = (const int*)d_in[6];
    const int*   batch = (const int*)d_in[7];
    float* out = (float*)d_out;
    float* gout = out + (size_t)N_NODESC * 3 * DIMC;
    char* ws = (char*)d_ws;

    size_t off = 0;
    auto alloc = [&](size_t bytes) {
        void* p = ws + off;
        off = (off + bytes + 255) & ~(size_t)255;
        return p;
    };
    // zero-region: bfill + bsum + bsq + dcnt contiguous -> single memset
    int*      bfill  = (int*)alloc(256 * sizeof(int));
    float*    bsum   = (float*)alloc(NLC * DIMC * sizeof(float));
    float*    bsq    = (float*)alloc(NLC * DIMC * sizeof(float));
    int*      dcnt   = (int*)alloc(NDEG * sizeof(int));
    size_t    zbytes = off;
    int2*     rowse  = (int2*)alloc((size_t)N_NODESC * sizeof(int2));
    int*      csr    = (int*)alloc((size_t)NBUCK * ECAP * sizeof(int));
    // xb aliases ebuf: ebuf (8 MB) is dead once csr_k completes; cvt_x runs after.
    unsigned* xb     = (unsigned*)alloc((size_t)N_NODESC * 64 * 4);
    unsigned* ebuf   = xb;
    unsigned* hpre   = (unsigned*)alloc((size_t)N_NODESC * 64 * 4);
    unsigned* hu     = (unsigned*)alloc((size_t)N_NODESC * 64 * 4);
    bf16_t*   Bp     = (bf16_t*)alloc((size_t)NLC * DIMC * DIMC * 2);
    float*    scale  = (float*)alloc(NLC * DIMC * sizeof(float));
    float*    shift  = (float*)alloc(NLC * DIMC * sizeof(float));
    int*      dbase  = (int*)alloc(NDEG * sizeof(int));
    int*      perm   = (int*)alloc((size_t)N_NODESC * sizeof(int));
    int*      gptr   = (int*)alloc((N_GRAPHSC + 1) * sizeof(int));

    hipMemsetAsync(ws, 0, zbytes, stream);

    int nEB = (N_EDGESC + EPB - 1) / EPB;
    bscat_k<<<nEB, 256, 0, stream>>>(ei, bfill, ebuf);
    csr_k<<<NBUCK, 256, 0, stream>>>(ebuf, bfill, rowse, csr);
    dhist_k<<<(N_NODESC + 255) / 256, 256, 0, stream>>>(rowse, dcnt);
    dscan_k<<<1, 64, 0, stream>>>(dcnt, dbase);
    dscat_k<<<(N_NODESC + 255) / 256, 256, 0, stream>>>(rowse, dbase, perm);
    // ebuf dead from here; xb reuses its space.
    pack_w<<<192, 256, 0, stream>>>(W, Bp);
    cvt_x<<<N_NODESC * 64 / 256, 256, 0, stream>>>(x, xb);
    gptr_k<<<(N_NODESC + 255) / 256, 256, 0, stream>>>(batch, gptr);

    for (int i = 0; i < NLC; ++i) {
        const unsigned* src = (i == 0) ? xb : hu;
        const float* scA = (i == 0) ? nullptr : (scale + (size_t)(i - 1) * DIMC);
        const float* shA = (i == 0) ? nullptr : (shift + (size_t)(i - 1) * DIMC);
        agg_k<<<N_NODESC / 16, 256, 0, stream>>>(src, eps_p, i, scA, shA, rowse, csr,
                                                 perm, hpre);
        gemm_k<<<(N_NODESC / 16 + 3) / 4, 256, 0, stream>>>(
            (const bf16_t*)hpre, Bp + (size_t)i * DIMC * DIMC, b + (size_t)i * DIMC,
            (bf16_t*)hu, bsum + (size_t)i * DIMC, bsq + (size_t)i * DIMC);
        fuse_k<<<N_GRAPHSC, 512, 0, stream>>>(
            hu, bsum + (size_t)i * DIMC, bsq + (size_t)i * DIMC,
            gamma + (size_t)i * DIMC, beta + (size_t)i * DIMC,
            scale + (size_t)i * DIMC, shift + (size_t)i * DIMC,
            gptr, out, gout, i * DIMC);
    }
}

// Round 12
// 412.211 us; speedup vs baseline: 2.4091x; 1.1633x over previous
//
#include <hip/hip_runtime.h>

#define N_NODESC 100000
#define N_EDGESC 1600000
#define N_GRAPHSC 512
#define DIMC 128
#define NLC 3
#define NBUCK 196      // ceil(100000/512)
#define EPB 4096       // edges per block in bucket scatter
#define ECAP 10240     // fixed per-bucket capacity (mean 8192, sigma~90)
#define BCAP 12288     // LDS staging capacity per bucket
#define NTILES 6250    // N_NODESC / 16

typedef __bf16 bf16_t;
typedef __bf16 bf16x2 __attribute__((ext_vector_type(2)));
typedef __bf16 bf16x4 __attribute__((ext_vector_type(4)));
typedef __bf16 bf16x8 __attribute__((ext_vector_type(8)));
typedef float f32x4 __attribute__((ext_vector_type(4)));

__device__ inline float bl(unsigned u) { union { unsigned x; float f; } c; c.x = u << 16; return c.f; }
__device__ inline float bh(unsigned u) { union { unsigned x; float f; } c; c.x = u & 0xffff0000u; return c.f; }
__device__ inline unsigned pk(float a, float b) {
    bf16x2 p; p[0] = (bf16_t)a; p[1] = (bf16_t)b;
    unsigned u; __builtin_memcpy(&u, &p, 4); return u;
}

// ---------- pack W^T (f32) into MFMA-B fragment order (bf16) ----------
__global__ void pack_w(const float* __restrict__ W, bf16_t* __restrict__ Bp) {
    int idx = blockIdx.x * 256 + threadIdx.x;
    if (idx >= NLC * 8 * 4 * 64 * 8) return;
    int j    = idx & 7;
    int lane = (idx >> 3) & 63;
    int kb   = (idx >> 9) & 3;
    int nt   = (idx >> 11) & 7;
    int i    = idx >> 14;
    int g = lane >> 4, c = lane & 15;
    int k = kb * 32 + ((j < 4) ? (4 * g + j) : (16 + 4 * g + (j - 4)));
    int n = nt * 16 + c;
    Bp[idx] = (bf16_t)W[i * DIMC * DIMC + n * DIMC + k];
}

// ---------- x -> bf16 compact ----------
__global__ void cvt_x(const float* __restrict__ x, unsigned* __restrict__ xb) {
    int i = blockIdx.x * 256 + threadIdx.x;
    if (i < N_NODESC * 64) {
        float2 v = ((const float2*)x)[i];
        xb[i] = pk(v.x, v.y);
    }
}

// ---------- bucketed CSR build (no global scan: fixed-capacity buckets) ----------
__global__ __launch_bounds__(256) void bscat_k(const int* __restrict__ ei,
                                               int* __restrict__ bfill,
                                               unsigned* __restrict__ ebuf) {
    __shared__ int h[256], pre[256], segb[256];
    __shared__ unsigned stage[EPB];
    __shared__ unsigned short sbb[EPB];
    int t = threadIdx.x;
    h[t] = 0;
    __syncthreads();
    int base = blockIdx.x * EPB;
    int dstv[16], srcv[16];
#pragma unroll
    for (int u = 0; u < 16; ++u) {
        int e = base + t + 256 * u;
        if (e < N_EDGESC) {
            dstv[u] = ei[N_EDGESC + e];
            srcv[u] = ei[e];
            atomicAdd(&h[dstv[u] >> 9], 1);
        } else dstv[u] = -1;
    }
    __syncthreads();
    int cnt = h[t];
    for (int off = 1; off < 256; off <<= 1) {
        int a = (t >= off) ? h[t - off] : 0;
        __syncthreads();
        h[t] += a;
        __syncthreads();
    }
    pre[t] = h[t] - cnt;
    if (t < NBUCK && cnt) segb[t] = atomicAdd(&bfill[t], cnt);
    __syncthreads();
    h[t] = pre[t];
    __syncthreads();
#pragma unroll
    for (int u = 0; u < 16; ++u) {
        if (dstv[u] >= 0) {
            int b = dstv[u] >> 9;
            int q = atomicAdd(&h[b], 1);
            stage[q] = ((unsigned)srcv[u] << 9) | (unsigned)(dstv[u] & 511);
            sbb[q] = (unsigned short)b;
        }
    }
    __syncthreads();
    int n = (base + EPB <= N_EDGESC) ? EPB : (N_EDGESC - base);
    for (int i = t; i < n; i += 256) {
        int b = sbb[i];
        ebuf[(long)b * ECAP + segb[b] + i - pre[b]] = stage[i];
    }
}

// one block per bucket: local histogram+scan -> rowse(start,end) + coalesced csr
__global__ __launch_bounds__(256) void csr_k(const unsigned* __restrict__ ebuf,
                                             const int* __restrict__ bfill,
                                             int2* __restrict__ rowse,
                                             int* __restrict__ csr) {
    __shared__ int hist[512], fill[512];
    __shared__ unsigned stage[BCAP];
    int t = threadIdx.x;
    int b = blockIdx.x;
    int cnt = bfill[b];
    long base = (long)b * ECAP;
    hist[t] = 0; hist[t + 256] = 0;
    __syncthreads();
    for (int e = t; e < cnt; e += 256)
        atomicAdd(&hist[ebuf[base + e] & 511], 1);
    __syncthreads();
    int c0 = hist[t], c1 = hist[t + 256];
    for (int off = 1; off < 512; off <<= 1) {
        int a0 = (t >= off) ? hist[t - off] : 0;
        int a1 = (t + 256 >= off) ? hist[t + 256 - off] : 0;
        __syncthreads();
        hist[t] += a0; hist[t + 256] += a1;
        __syncthreads();
    }
    int p0 = hist[t] - c0, p1 = hist[t + 256] - c1;
    fill[t] = p0; fill[t + 256] = p1;
    int n0 = b * 512;
    if (n0 + t < N_NODESC) {
        int2 r; r.x = (int)base + p0; r.y = (int)base + p0 + c0;
        rowse[n0 + t] = r;
    }
    if (n0 + t + 256 < N_NODESC) {
        int2 r; r.x = (int)base + p1; r.y = (int)base + p1 + c1;
        rowse[n0 + t + 256] = r;
    }
    __syncthreads();
    for (int e = t; e < cnt; e += 256) {
        unsigned p = ebuf[base + e];
        int q = atomicAdd(&fill[p & 511], 1);
        unsigned s = p >> 9;
        if (q < BCAP) stage[q] = s; else csr[base + q] = s;
    }
    __syncthreads();
    int m = cnt < BCAP ? cnt : BCAP;
    for (int i = t; i < m; i += 256) csr[base + i] = stage[i];
}

// ---------- graph ranges from sorted batch ----------
__global__ void gptr_k(const int* __restrict__ batch, int* __restrict__ gptr) {
    int n = blockIdx.x * 256 + threadIdx.x;
    if (n >= N_NODESC) return;
    int b = batch[n];
    if (n == 0) for (int g = 0; g <= b; ++g) gptr[g] = 0;
    if (n == N_NODESC - 1) {
        for (int g = b + 1; g <= N_GRAPHSC; ++g) gptr[g] = N_NODESC;
    } else {
        int b2 = batch[n + 1];
        for (int g = b + 1; g <= b2; ++g) gptr[g] = n + 1;
    }
}

// ---------- aggregation (bf16 uint4 gather, 4 nodes/wave, unroll 8, BN folded) ----------
// h_pre = sc * ((1+eps)*self + sum_nb) + (deg+1+eps) * sh   [sc=1,sh=0 for layer 0]
__global__ __launch_bounds__(256) void agg_k(const unsigned* __restrict__ src,
                                             const float* __restrict__ epsp, int layer,
                                             const float* __restrict__ scale,
                                             const float* __restrict__ shift,
                                             const int2* __restrict__ rowse,
                                             const int* __restrict__ csr,
                                             unsigned* __restrict__ hpre) {
    int t = threadIdx.x;
    int wave = t >> 6, lane = t & 63;
    int h = lane >> 4;       // which node of the 4
    int c = lane & 15;       // uint4 chunk (16 B) within 256 B row
    int n = blockIdx.x * 16 + wave * 4 + h;
    const uint4* rows = (const uint4*)src;
    float eps = epsp[layer];
    int2 re = rowse[n];
    int jb = re.x, je = re.y;
    uint4 us = rows[(long)n * 16 + c];
    float a0 = 0.f, a1 = 0.f, a2 = 0.f, a3 = 0.f;
    float a4 = 0.f, a5 = 0.f, a6 = 0.f, a7 = 0.f;
    int j = jb;
    for (; j + 8 <= je; j += 8) {
        uint4 u0 = rows[(long)csr[j] * 16 + c];
        uint4 u1 = rows[(long)csr[j + 1] * 16 + c];
        uint4 u2 = rows[(long)csr[j + 2] * 16 + c];
        uint4 u3 = rows[(long)csr[j + 3] * 16 + c];
        uint4 u4 = rows[(long)csr[j + 4] * 16 + c];
        uint4 u5 = rows[(long)csr[j + 5] * 16 + c];
        uint4 u6 = rows[(long)csr[j + 6] * 16 + c];
        uint4 u7 = rows[(long)csr[j + 7] * 16 + c];
        a0 += (bl(u0.x) + bl(u1.x) + bl(u2.x) + bl(u3.x))
            + (bl(u4.x) + bl(u5.x) + bl(u6.x) + bl(u7.x));
        a1 += (bh(u0.x) + bh(u1.x) + bh(u2.x) + bh(u3.x))
            + (bh(u4.x) + bh(u5.x) + bh(u6.x) + bh(u7.x));
        a2 += (bl(u0.y) + bl(u1.y) + bl(u2.y) + bl(u3.y))
            + (bl(u4.y) + bl(u5.y) + bl(u6.y) + bl(u7.y));
        a3 += (bh(u0.y) + bh(u1.y) + bh(u2.y) + bh(u3.y))
            + (bh(u4.y) + bh(u5.y) + bh(u6.y) + bh(u7.y));
        a4 += (bl(u0.z) + bl(u1.z) + bl(u2.z) + bl(u3.z))
            + (bl(u4.z) + bl(u5.z) + bl(u6.z) + bl(u7.z));
        a5 += (bh(u0.z) + bh(u1.z) + bh(u2.z) + bh(u3.z))
            + (bh(u4.z) + bh(u5.z) + bh(u6.z) + bh(u7.z));
        a6 += (bl(u0.w) + bl(u1.w) + bl(u2.w) + bl(u3.w))
            + (bl(u4.w) + bl(u5.w) + bl(u6.w) + bl(u7.w));
        a7 += (bh(u0.w) + bh(u1.w) + bh(u2.w) + bh(u3.w))
            + (bh(u4.w) + bh(u5.w) + bh(u6.w) + bh(u7.w));
    }
    for (; j + 4 <= je; j += 4) {
        uint4 u0 = rows[(long)csr[j] * 16 + c];
        uint4 u1 = rows[(long)csr[j + 1] * 16 + c];
        uint4 u2 = rows[(long)csr[j + 2] * 16 + c];
        uint4 u3 = rows[(long)csr[j + 3] * 16 + c];
        a0 += bl(u0.x) + bl(u1.x) + bl(u2.x) + bl(u3.x);
        a1 += bh(u0.x) + bh(u1.x) + bh(u2.x) + bh(u3.x);
        a2 += bl(u0.y) + bl(u1.y) + bl(u2.y) + bl(u3.y);
        a3 += bh(u0.y) + bh(u1.y) + bh(u2.y) + bh(u3.y);
        a4 += bl(u0.z) + bl(u1.z) + bl(u2.z) + bl(u3.z);
        a5 += bh(u0.z) + bh(u1.z) + bh(u2.z) + bh(u3.z);
        a6 += bl(u0.w) + bl(u1.w) + bl(u2.w) + bl(u3.w);
        a7 += bh(u0.w) + bh(u1.w) + bh(u2.w) + bh(u3.w);
    }
    for (; j < je; ++j) {
        uint4 u = rows[(long)csr[j] * 16 + c];
        a0 += bl(u.x); a1 += bh(u.x); a2 += bl(u.y); a3 += bh(u.y);
        a4 += bl(u.z); a5 += bh(u.z); a6 += bl(u.w); a7 += bh(u.w);
    }
    float se = 1.f + eps;
    float t0 = se * bl(us.x) + a0, t1 = se * bh(us.x) + a1;
    float t2 = se * bl(us.y) + a2, t3 = se * bh(us.y) + a3;
    float t4 = se * bl(us.z) + a4, t5 = se * bh(us.z) + a5;
    float t6 = se * bl(us.w) + a6, t7 = se * bh(us.w) + a7;
    uint4 o;
    if (scale) {
        float cdeg = (float)(je - jb) + se;
        int f = 8 * c;
        o.x = pk(scale[f] * t0 + cdeg * shift[f],
                 scale[f + 1] * t1 + cdeg * shift[f + 1]);
        o.y = pk(scale[f + 2] * t2 + cdeg * shift[f + 2],
                 scale[f + 3] * t3 + cdeg * shift[f + 3]);
        o.z = pk(scale[f + 4] * t4 + cdeg * shift[f + 4],
                 scale[f + 5] * t5 + cdeg * shift[f + 5]);
        o.w = pk(scale[f + 6] * t6 + cdeg * shift[f + 6],
                 scale[f + 7] * t7 + cdeg * shift[f + 7]);
    } else {
        o.x = pk(t0, t1); o.y = pk(t2, t3); o.z = pk(t4, t5); o.w = pk(t6, t7);
    }
    ((uint4*)hpre)[(long)n * 16 + c] = o;
}

// ---------- GEMM: relu(h_pre @ W^T + b) -> hu ; 4 tiles/wave (256 rows/block) ----------
__global__ __launch_bounds__(256) void gemm_k(const bf16_t* __restrict__ hb,
                                              const bf16_t* __restrict__ Bp,
                                              const float* __restrict__ bias,
                                              bf16_t* __restrict__ hu,
                                              float* __restrict__ bsum,
                                              float* __restrict__ bsq) {
    __shared__ bf16_t Bl[8 * 4 * 64 * 8];  // 32 KiB
    __shared__ float lsum[DIMC], lsq[DIMC];
    int t = threadIdx.x;
    {
        const int4* s = (const int4*)Bp;
        int4* dl = (int4*)Bl;
#pragma unroll
        for (int u = 0; u < 8; ++u) dl[t + 256 * u] = s[t + 256 * u];
    }
    if (t < DIMC) { lsum[t] = 0.f; lsq[t] = 0.f; }
    __syncthreads();
    int wave = t >> 6, lane = t & 63;
    int col = lane & 15, g = lane >> 4;
    for (int q = 0; q < 4; ++q) {
        int tile = blockIdx.x * 16 + wave * 4 + q;
        if (tile >= NTILES) break;
        int row0 = tile * 16;
        const bf16_t* arow = hb + (long)(row0 + col) * DIMC;
        bf16x8 a[4];
#pragma unroll
        for (int kb = 0; kb < 4; ++kb) {
            bf16x4 lo = *(const bf16x4*)(arow + kb * 32 + 4 * g);
            bf16x4 hi = *(const bf16x4*)(arow + kb * 32 + 16 + 4 * g);
            bf16x8 av;
            av[0] = lo[0]; av[1] = lo[1]; av[2] = lo[2]; av[3] = lo[3];
            av[4] = hi[0]; av[5] = hi[1]; av[6] = hi[2]; av[7] = hi[3];
            a[kb] = av;
        }
#pragma unroll
        for (int nt = 0; nt < 8; ++nt) {
            f32x4 acc = {0.f, 0.f, 0.f, 0.f};
#pragma unroll
            for (int kb = 0; kb < 4; ++kb) {
                bf16x8 bv = *(const bf16x8*)&Bl[((nt * 4 + kb) * 64 + lane) * 8];
                acc = __builtin_amdgcn_mfma_f32_16x16x32_bf16(a[kb], bv, acc, 0, 0, 0);
            }
            int f = nt * 16 + col;
            float bi = bias[f];
            float ss = 0.f, sq = 0.f;
#pragma unroll
            for (int r = 0; r < 4; ++r) {
                float v = fmaxf(acc[r] + bi, 0.f);
                float vf = (float)(bf16_t)v;
                ss += vf; sq += vf * vf;
                float vo = __shfl_xor(vf, 1);
                unsigned u = pk(vf, vo);
                unsigned u2 = (unsigned)__shfl_xor((int)u, 2);
                if ((col & 3) == 0) {
                    uint2 st; st.x = u; st.y = u2;
                    *(uint2*)&hu[(long)(row0 + g * 4 + r) * DIMC + nt * 16 + col] = st;
                }
            }
            ss += __shfl_xor(ss, 16);
            ss += __shfl_xor(ss, 32);
            sq += __shfl_xor(sq, 16);
            sq += __shfl_xor(sq, 32);
            if (g == 0) { atomicAdd(&lsum[f], ss); atomicAdd(&lsq[f], sq); }
        }
    }
    __syncthreads();
    if (t < DIMC) atomicAdd(&bsum[t], lsum[t]);
    else if (t < 2 * DIMC) atomicAdd(&bsq[t - DIMC], lsq[t - DIMC]);
}

// ---------- fused BN-param + BN-apply (z_cat) + global_add_pool (g_cat) ----------
__global__ __launch_bounds__(512) void fuse_k(const unsigned* __restrict__ hu32,
                                              const float* __restrict__ bsum,
                                              const float* __restrict__ bsq,
                                              const float* __restrict__ gamma,
                                              const float* __restrict__ beta,
                                              float* __restrict__ scaleOut,
                                              float* __restrict__ shiftOut,
                                              const int* __restrict__ gptr,
                                              float* __restrict__ out,
                                              float* __restrict__ gout, int layerOff) {
    __shared__ float red[8][DIMC];
    __shared__ float sc[DIMC], sh[DIMC];
    int g = blockIdx.x, t = threadIdx.x;
    if (t < DIMC) {
        float mu = bsum[t] * (1.0f / N_NODESC);
        float var = bsq[t] * (1.0f / N_NODESC) - mu * mu;
        float s = rsqrtf(var + 1e-5f) * gamma[t];
        float b = beta[t] - mu * s;
        sc[t] = s; sh[t] = b;
        if (g == 0) { scaleOut[t] = s; shiftOut[t] = b; }
    }
    __syncthreads();
    int q = t >> 6, lane = t & 63;
    int s0i = gptr[g], e0i = gptr[g + 1];
    float sc0 = sc[2 * lane], sc1 = sc[2 * lane + 1];
    float sh0 = sh[2 * lane], sh1 = sh[2 * lane + 1];
    float p0 = 0.f, p1 = 0.f;
    for (int n = s0i + q; n < e0i; n += 8) {
        unsigned u = hu32[(long)n * 64 + lane];
        float v0 = bl(u), v1 = bh(u);
        p0 += v0; p1 += v1;
        float2 w;
        w.x = sc0 * v0 + sh0;
        w.y = sc1 * v1 + sh1;
        *(float2*)&out[(long)n * (3 * DIMC) + layerOff + 2 * lane] = w;
    }
    red[q][2 * lane] = p0;
    red[q][2 * lane + 1] = p1;
    __syncthreads();
    if (t < DIMC) {
        float sum = 0.f;
#pragma unroll
        for (int k = 0; k < 8; ++k) sum += red[k][t];
        float cnt = (float)(e0i - s0i);
        gout[(long)g * (3 * DIMC) + layerOff + t] = sc[t] * sum + cnt * sh[t];
    }
}

extern "C" void kernel_launch(void* const* d_in, const int* in_sizes, int n_in,
                              void* d_out, int out_size, void* d_ws, size_t ws_size,
                              hipStream_t stream) {
    const float* x     = (const float*)d_in[0];
    const float* W     = (const float*)d_in[1];
    const float* b     = (const float*)d_in[2];
    const float* eps_p = (const float*)d_in[3];
    const float* gamma = (const float*)d_in[4];
    const float* beta  = (const float*)d_in[5];
    const int*   ei    = (const int*)d_in[6];
    const int*   batch = (const int*)d_in[7];
    float* out = (float*)d_out;
    float* gout = out + (size_t)N_NODESC * 3 * DIMC;
    char* ws = (char*)d_ws;

    size_t off = 0;
    auto alloc = [&](size_t bytes) {
        void* p = ws + off;
        off = (off + bytes + 255) & ~(size_t)255;
        return p;
    };
    // zero-region: bfill + bsum + bsq contiguous -> single memset
    int*      bfill  = (int*)alloc(256 * sizeof(int));
    float*    bsum   = (float*)alloc(NLC * DIMC * sizeof(float));
    float*    bsq    = (float*)alloc(NLC * DIMC * sizeof(float));
    size_t    zbytes = off;
    int2*     rowse  = (int2*)alloc((size_t)N_NODESC * sizeof(int2));
    int*      csr    = (int*)alloc((size_t)NBUCK * ECAP * sizeof(int));
    // xb aliases ebuf: ebuf (8 MB) is dead once csr_k completes; cvt_x runs after.
    unsigned* xb     = (unsigned*)alloc((size_t)N_NODESC * 64 * 4);
    unsigned* ebuf   = xb;
    unsigned* hpre   = (unsigned*)alloc((size_t)N_NODESC * 64 * 4);
    unsigned* hu     = (unsigned*)alloc((size_t)N_NODESC * 64 * 4);
    bf16_t*   Bp     = (bf16_t*)alloc((size_t)NLC * DIMC * DIMC * 2);
    float*    scale  = (float*)alloc(NLC * DIMC * sizeof(float));
    float*    shift  = (float*)alloc(NLC * DIMC * sizeof(float));
    int*      gptr   = (int*)alloc((N_GRAPHSC + 1) * sizeof(int));

    hipMemsetAsync(ws, 0, zbytes, stream);

    int nEB = (N_EDGESC + EPB - 1) / EPB;
    bscat_k<<<nEB, 256, 0, stream>>>(ei, bfill, ebuf);
    csr_k<<<NBUCK, 256, 0, stream>>>(ebuf, bfill, rowse, csr);
    // ebuf dead from here; xb reuses its space.
    pack_w<<<192, 256, 0, stream>>>(W, Bp);
    cvt_x<<<N_NODESC * 64 / 256, 256, 0, stream>>>(x, xb);
    gptr_k<<<(N_NODESC + 255) / 256, 256, 0, stream>>>(batch, gptr);

    for (int i = 0; i < NLC; ++i) {
        const unsigned* src = (i == 0) ? xb : hu;
        const float* scA = (i == 0) ? nullptr : (scale + (size_t)(i - 1) * DIMC);
        const float* shA = (i == 0) ? nullptr : (shift + (size_t)(i - 1) * DIMC);
        agg_k<<<N_NODESC / 16, 256, 0, stream>>>(src, eps_p, i, scA, shA, rowse, csr,
                                                 hpre);
        gemm_k<<<(NTILES + 15) / 16, 256, 0, stream>>>(
            (const bf16_t*)hpre, Bp + (size_t)i * DIMC * DIMC, b + (size_t)i * DIMC,
            (bf16_t*)hu, bsum + (size_t)i * DIMC, bsq + (size_t)i * DIMC);
        fuse_k<<<N_GRAPHSC, 512, 0, stream>>>(
            hu, bsum + (size_t)i * DIMC, bsq + (size_t)i * DIMC,
            gamma + (size_t)i * DIMC, beta + (size_t)i * DIMC,
            scale + (size_t)i * DIMC, shift + (size_t)i * DIMC,
            gptr, out, gout, i * DIMC);
    }
}